// Round 10
// baseline (42.591 us; speedup 1.0000x reference)
//
#include <hip/hip_runtime.h>

#define BB 4096
#define TT 80
#define VV 10000
#define EE 100
#define HH 64
#define STR 68    // fp16 row stride: 136 B/row; bursts at bank minimum (R6-verified)
#define STRP 68   // f32 row stride for P partials

typedef _Float16 f16x8 __attribute__((ext_vector_type(8)));
typedef _Float16 f16x4 __attribute__((ext_vector_type(4)));
typedef __attribute__((ext_vector_type(4))) float f4v;   // 4 fp32

// Transposed compute: D = A(W^T frag) * B(state frag) + C -> lane holds
// (batch row = l&15, 4 adjacent hidden cols = 4*(l>>4)+q)
#define MFMA(w, s, c) __builtin_amdgcn_mfma_f32_16x16x32_f16((w), (s), (c), 0, 0, 0)

// Raw barrier: drains LDS ops (lgkm) but lets global loads stay in flight.
#define BAR() do { asm volatile("s_waitcnt lgkmcnt(0)" ::: "memory"); \
                   __builtin_amdgcn_s_barrier();                      \
                   asm volatile("" ::: "memory"); } while (0)

// tanh(x) = 1 - 2/(exp(2x)+1). No clamp: +inf -> 1, -inf -> -1.
__device__ __forceinline__ float fast_tanh(float x) {
    float e = __builtin_amdgcn_exp2f(x * 2.8853900817779268f); // exp(2x)
    return 1.0f - 2.0f * __builtin_amdgcn_rcpf(e + 1.0f);
}

// Weight fragment (hi/lo fp16) for W[k][c]: frag elem i <- W[32*kf + 8*g + i][c]
__device__ __forceinline__ void load_wfrag(const float* __restrict__ W, int kf, int g,
                                           int c, f16x8& hi, f16x8& lo) {
    union { _Float16 h[8]; f16x8 v; } th, tl;
#pragma unroll
    for (int i = 0; i < 8; ++i) {
        float wv = W[(32 * kf + 8 * g + i) * HH + c];
        _Float16 hf = (_Float16)wv;          // RNE
        th.h[i] = hf;
        tl.h[i] = (_Float16)(wv - (float)hf);
    }
    hi = th.v;
    lo = tl.v;
}

// emb2h[v][j] = fp16( b0[j] + sum_e emb[v][e] * Wx0[e][j] )  (unchanged from R8)
__global__ __launch_bounds__(256) void emb2_kernel(const float* __restrict__ emb,
                                                   const float* __restrict__ Wx0,
                                                   const float* __restrict__ b0,
                                                   _Float16* __restrict__ emb2h) {
    const int tid = threadIdx.x;
    const int wid = tid >> 6;
    const int l = tid & 63;
    const int g = l >> 4;
    const int r16 = l & 15;
    const int c = 16 * wid + r16;
    const int jcol = 16 * wid + 4 * g;
    const int vr = blockIdx.x * 16 + r16;   // VV % 16 == 0

    f16x8 wa[4];   // Wx0^T hi frags, K = 128 (zero-pad e >= 100)
#pragma unroll
    for (int kf = 0; kf < 4; ++kf) {
        union { _Float16 h[8]; f16x8 v; } t;
#pragma unroll
        for (int i = 0; i < 8; ++i) {
            int e = 32 * kf + 8 * g + i;
            t.h[i] = (e < EE) ? (_Float16)Wx0[e * HH + c] : (_Float16)0.f;
        }
        wa[kf] = t.v;
    }
    const float* er = emb + (size_t)vr * EE;
    f4v acc = *(const f4v*)&b0[jcol];
#pragma unroll
    for (int kf = 0; kf < 4; ++kf) {
        union { _Float16 h[8]; f16x8 v; } tb;
#pragma unroll
        for (int i = 0; i < 8; ++i) {
            int e = 32 * kf + 8 * g + i;
            tb.h[i] = (e < EE) ? (_Float16)er[e] : (_Float16)0.f;
        }
        acc = MFMA(wa[kf], tb.v, acc);
    }
    f16x4 o;
#pragma unroll
    for (int q = 0; q < 4; ++q) o[q] = (_Float16)acc[q];
    *(f16x4*)&emb2h[(size_t)vr * HH + jcol] = o;
}

// 3-stage pipeline: 256 blocks x 768 thr (12 waves = 3/SIMD), 16 rows/block.
// Role 0 (waves 0-3,  L0 ): h0(q)   = tanh(x(q) + Wh0^T @ h0(q-1))
// Role 1 (waves 4-7,  L1a): P(q)    = b1 + Wx1^T @ h0(q-1)        [no tanh]
// Role 2 (waves 8-11, L1b): h1(q-2) = tanh(P(q-1) + Wh1^T @ h1(q-3))
// P passes through LDS raw f32 in D-layout (no transpose: written as f4v,
// read back as the MFMA C-init). Every wave: ONE weight matrix, 4 MFMA.
// h1 lags h0 by 2 phases; 82 phases total. One raw barrier per phase.
__global__ __launch_bounds__(768, 1) void rnn_pipe(
    const int* __restrict__ tokens, const _Float16* __restrict__ emb2,
    const float* __restrict__ Wh0, const float* __restrict__ Wx1,
    const float* __restrict__ Wh1, const float* __restrict__ b1,
    const float* __restrict__ Wout, const float* __restrict__ bout,
    float* __restrict__ out) {
    __shared__ __align__(16) _Float16 H0[2][16][STR];
    __shared__ __align__(16) _Float16 H1[2][16][STR];
    __shared__ __align__(16) float PP[2][16][STRP];
    __shared__ __align__(16) int tokT[TT][16];   // [t][row], byte-scaled (<<7)
    __shared__ float Pred[4][16];

    const int tid = threadIdx.x;
    const int w12 = tid >> 6;        // 0..11
    const int l = tid & 63;
    const int g = l >> 4;
    const int r16 = l & 15;          // my batch row
    const int role = w12 >> 2;       // 0 = L0, 1 = L1a, 2 = L1b
    const int tile = w12 & 3;        // hidden-column tile
    const int c = 16 * tile + r16;   // weight column for A-fragment loads
    const int jcol = 16 * tile + 4 * g;  // my 4 output cols
    const int R = blockIdx.x * 16;   // base batch row

    for (int i = tid; i < 16 * TT; i += 768) {
        int r = i / TT, t = i - r * TT;              // coalesced global read
        tokT[t][r] = tokens[R * TT + i] << 7;        // row stride 64 fp16 = 128 B
    }

    // Each role owns exactly one weight matrix (hi/lo fp16 fragments).
    const float* Wsel = (role == 0) ? Wh0 : (role == 1 ? Wx1 : Wh1);
    f16x8 wAh[2], wAl[2];
    load_wfrag(Wsel, 0, g, c, wAh[0], wAl[0]);
    load_wfrag(Wsel, 1, g, c, wAh[1], wAl[1]);
    const f4v b1v = *(const f4v*)&b1[jcol];
    const f4v wov = *(const f4v*)&Wout[jcol];
    const f4v z4 = {0.f, 0.f, 0.f, 0.f};
    const char* ebase = (const char*)emb2 + (size_t)jcol * 2;

    BAR();   // tokens staged

    f16x8 as0 = (f16x8)0, as1 = (f16x8)0;   // consumed state frags (h0 or h1)
    f16x4 xc = (f16x4)0, xn = (f16x4)0;     // raw fp16 gathers (L0 only)

    // ---- phase 0: L0 writes h0(0) = tanh(x(0)) ----
    if (role == 0) {
        xc = *(const f16x4*)(ebase + tokT[0][r16]);
        xn = *(const f16x4*)(ebase + tokT[1][r16]);
        f16x4 ph;
#pragma unroll
        for (int q = 0; q < 4; ++q) ph[q] = (_Float16)fast_tanh((float)xc[q]);
        *(f16x4*)&H0[0][r16][jcol] = ph;
        xc = xn;
    }
    BAR();
    if (role != 2) {   // L0 and L1a consume h0
        as0 = *(const f16x8*)&H0[0][r16][8 * g];
        as1 = *(const f16x8*)&H0[0][r16][32 + 8 * g];
    }
    // L1b's as stays zero (h1(-1) = 0)

    // ---- main loop q = 1..80 ----
#pragma unroll 2
    for (int q = 1; q <= 80; ++q) {
        const int par = q & 1;
        if (role == 0) {
            if (q <= TT - 1) {
                // prefetch x(q+1) (clamped); floats across BAR to next use
                int pn = (q + 1 <= TT - 1) ? q + 1 : TT - 1;
                xn = *(const f16x4*)(ebase + tokT[pn][r16]);
                f4v C1 = {(float)xc[0], (float)xc[1], (float)xc[2], (float)xc[3]};
                C1 = MFMA(wAh[0], as0, C1);
                C1 = MFMA(wAh[1], as1, C1);
                f4v C2 = MFMA(wAl[0], as0, z4);
                C2 = MFMA(wAl[1], as1, C2);
                f4v acc = C1 + C2;
                f16x4 ph;
#pragma unroll
                for (int u = 0; u < 4; ++u) ph[u] = (_Float16)fast_tanh(acc[u]);
                *(f16x4*)&H0[par][r16][jcol] = ph;
                xc = xn;
            }
        } else if (role == 1) {
            // P(q) = b1 + Wx1^T @ h0(q-1) — raw f32, no tanh
            f4v C1 = b1v;
            C1 = MFMA(wAh[0], as0, C1);
            C1 = MFMA(wAh[1], as1, C1);
            f4v C2 = MFMA(wAl[0], as0, z4);
            C2 = MFMA(wAl[1], as1, C2);
            f4v P = C1 + C2;
            *(f4v*)&PP[par][r16][jcol] = P;
        } else {
            if (q >= 2) {
                // h1(q-2) = tanh(P(q-1) + Wh1^T @ h1(q-3))
                f4v C1 = *(const f4v*)&PP[par ^ 1][r16][jcol];
                C1 = MFMA(wAh[0], as0, C1);
                C1 = MFMA(wAh[1], as1, C1);
                f4v C2 = MFMA(wAl[0], as0, z4);
                C2 = MFMA(wAl[1], as1, C2);
                f4v acc = C1 + C2;
                f16x4 ph;
#pragma unroll
                for (int u = 0; u < 4; ++u) ph[u] = (_Float16)fast_tanh(acc[u]);
                *(f16x4*)&H1[par][r16][jcol] = ph;
            }
        }
        BAR();
        if (role != 2) {
            if (q <= TT - 1) {   // h0(q) for next phase
                as0 = *(const f16x8*)&H0[par][r16][8 * g];
                as1 = *(const f16x8*)&H0[par][r16][32 + 8 * g];
            }
        } else {
            if (q >= 2) {        // h1(q-2) for next phase
                as0 = *(const f16x8*)&H1[par][r16][8 * g];
                as1 = *(const f16x8*)&H1[par][r16][32 + 8 * g];
            }
        }
    }

    // ---- phase 81: L1b final h1(79) = tanh(P(80) + Wh1^T @ h1(78)),
    //      in-register, straight into the output epilogue ----
    if (role == 2) {
        f4v C1 = *(const f4v*)&PP[0][r16][jcol];   // P(80), written q=80 (par 0)
        C1 = MFMA(wAh[0], as0, C1);
        C1 = MFMA(wAh[1], as1, C1);
        f4v C2 = MFMA(wAl[0], as0, z4);
        C2 = MFMA(wAl[1], as1, C2);
        f4v acc = C1 + C2;
        // out = sigmoid(h1(79) @ Wout + bout): lane holds 4 cols of row r16
        float pp = fast_tanh(acc[0]) * wov[0];
        pp = fmaf(fast_tanh(acc[1]), wov[1], pp);
        pp = fmaf(fast_tanh(acc[2]), wov[2], pp);
        pp = fmaf(fast_tanh(acc[3]), wov[3], pp);
        pp += __shfl_xor(pp, 16, 64);   // sum over g-groups
        pp += __shfl_xor(pp, 32, 64);
        if (l < 16) Pred[tile][l] = pp;
    }
    BAR();
    if (tid < 16) {
        float logit = Pred[0][tid] + Pred[1][tid] + Pred[2][tid] +
                      Pred[3][tid] + bout[0];
        out[R + tid] = __builtin_amdgcn_rcpf(
            1.0f + __builtin_amdgcn_exp2f(-1.4426950408889634f * logit));
    }
}

extern "C" void kernel_launch(void* const* d_in, const int* in_sizes, int n_in,
                              void* d_out, int out_size, void* d_ws, size_t ws_size,
                              hipStream_t stream) {
    const int*   tokens = (const int*)  d_in[0];
    const float* emb    = (const float*)d_in[1];
    const float* Wx0    = (const float*)d_in[2];
    const float* Wh0    = (const float*)d_in[3];
    const float* b0     = (const float*)d_in[4];
    const float* Wx1    = (const float*)d_in[5];
    const float* Wh1    = (const float*)d_in[6];
    const float* b1     = (const float*)d_in[7];
    const float* Wout   = (const float*)d_in[8];
    const float* bout   = (const float*)d_in[9];
    float* out  = (float*)d_out;
    _Float16* emb2h = (_Float16*)d_ws;   // VV*HH fp16 = 1.28 MB

    emb2_kernel<<<VV / 16, 256, 0, stream>>>(emb, Wx0, b0, emb2h);
    rnn_pipe<<<BB / 16, 768, 0, stream>>>(tokens, emb2h, Wh0, Wx1, Wh1, b1,
                                          Wout, bout, out);
}